// Round 2
// baseline (198.042 us; speedup 1.0000x reference)
//
#include <hip/hip_runtime.h>
#include <hip/hip_bf16.h>

typedef __attribute__((ext_vector_type(8))) short short8;
typedef __attribute__((ext_vector_type(16))) float floatx16;

#define BDIM 512

constexpr int kCIN = 256, kCOUT = 256, kH = 64, kW = 64;
constexpr int BK = 32;                  // ci per chunk
constexpr int NCHUNK = kCIN / BK;       // 8
constexpr int ROWS = 4;                 // output rows per block
constexpr int XR = ROWS + 2, XC = 66, NPIX = XR * XC;  // 396 halo pixels
constexpr int HW = kH * kW;
constexpr int NSTEP = NCHUNK * 9;       // 72

// 16B-granule XOR swizzle within pairs of 64B rows: conflict-free for
// consecutive-row b128 reads (measured 0 conflicts in round 1)
__device__ __forceinline__ int swz16(int row, int g) {
    return ((g ^ ((row >> 1) & 3)) << 4);
}

__device__ __forceinline__ unsigned short f2bf(float f) {
    unsigned u = __float_as_uint(f);
    u += 0x7fffu + ((u >> 16) & 1u);   // RNE
    return (unsigned short)(u >> 16);
}

// weight[co][ci][kh][kw] fp32  ->  Wt[kk][co][ci] bf16  (kk = kh*3+kw)
__global__ void wt_transform_kernel(const float* __restrict__ wsrc,
                                    unsigned short* __restrict__ wt) {
    int idx = blockIdx.x * 256 + threadIdx.x;
    if (idx >= 9 * 256 * 256) return;
    int ci = idx & 255;
    int co = (idx >> 8) & 255;
    int kk = idx >> 16;
    wt[idx] = f2bf(wsrc[(co * 256 + ci) * 9 + kk]);
}

// Block: 256 cout x 256 pixels (4 rows). 8 waves = 2(co-group) x 4(row).
// Wave tile: 128 co x 64 pix, 4x2 frags of 32x32x16 MFMA.
__global__ __launch_bounds__(BDIM, 2)
void conv3x3_mfma_kernel(const float* __restrict__ x,
                         const unsigned short* __restrict__ wt,
                         const float* __restrict__ bias,
                         float* __restrict__ out) {
    __shared__ __align__(16) char xs[NPIX * 64];    // [pix=r*66+c][32 ci] bf16, swizzled
    __shared__ __align__(16) char ws[2][256 * 64];  // [co][32 ci] bf16, swizzled, dbuf

    const int bid = blockIdx.x;
    const int b  = bid >> 4;            // 16 h-tiles per image
    const int h0 = (bid & 15) * ROWS;

    const int tid = threadIdx.x;
    const int wv  = tid >> 6;
    const int l   = tid & 63;
    const int l31 = l & 31;
    const int hi2 = l >> 5;
    const int cog  = (wv & 1) * 128;    // wave's cout base
    const int wrow = wv >> 1;           // wave's output row (0..3)

    const float* xb = x + (size_t)b * kCIN * HW;

    floatx16 acc[4][2] = {};            // [co frag][pix frag]

    // ---- W staging: global_load_lds, linear LDS dest + pre-swizzled global src ----
    // wave wv covers co rows [it*128 + wv*16, +16); lane l -> co = row0 + l/4,
    // physical 16B slot (l&3) holds logical granule (l&3)^((co>>1)&3).
    auto stageW = [&](int st) {         // st = chunk*9 + kk
        int chunk = st / 9, kk = st - chunk * 9;
        const unsigned short* wp = wt + (size_t)kk * 65536 + chunk * BK;
        char* wbuf = ws[st & 1];
        #pragma unroll
        for (int it = 0; it < 2; ++it) {
            int row0 = it * 128 + wv * 16;
            int co = row0 + (l >> 2);
            int g  = (l & 3) ^ ((co >> 1) & 3);
            const unsigned short* src = wp + co * 256 + g * 8;
            __builtin_amdgcn_global_load_lds(
                (const __attribute__((address_space(1))) unsigned int*)src,
                (__attribute__((address_space(3))) unsigned int*)(wbuf + row0 * 64),
                16, 0, 0);
        }
    };

    // ---- x halo staging: rows h0-1..h0+ROWS, cols -1..64, 32 ci (fp32->bf16) ----
    auto stageX = [&](int chunk) {
        const int ci0 = chunk * BK;
        for (int t = tid; t < NPIX * 4; t += BDIM) {
            int g = t / NPIX;
            int rem = t - g * NPIX;
            int r = rem / XC;
            int c = rem - r * XC;
            int ih = h0 - 1 + r;
            int iw = c - 1;
            float v[8];
            if ((unsigned)ih < (unsigned)kH && (unsigned)iw < (unsigned)kW) {
                const float* p = xb + (size_t)(ci0 + g * 8) * HW + ih * kW + iw;
                #pragma unroll
                for (int j = 0; j < 8; ++j) v[j] = p[(size_t)j * HW];
            } else {
                #pragma unroll
                for (int j = 0; j < 8; ++j) v[j] = 0.f;
            }
            union { short8 s8; unsigned short u[8]; } pk;
            #pragma unroll
            for (int j = 0; j < 8; ++j) pk.u[j] = f2bf(v[j]);
            int pix = r * XC + c;
            *(short8*)(xs + pix * 64 + swz16(pix, g)) = pk.s8;
        }
    };

    stageX(0);
    stageW(0);
    __syncthreads();

    for (int st = 0; st < NSTEP; ++st) {
        const int chunk = st / 9;
        const int kk = st - chunk * 9;
        if (st < NSTEP - 1) stageW(st + 1);   // prefetch into other buffer

        const char* wbuf = ws[st & 1];
        const int kh = kk / 3, kwo = kk - kh * 3;
        const int r = wrow + kh;

        short8 a[2][4], bfr[2][2];
        #pragma unroll
        for (int s = 0; s < 2; ++s) {
            const int g = s * 2 + hi2;
            #pragma unroll
            for (int i = 0; i < 4; ++i) {
                int co = cog + i * 32 + l31;
                a[s][i] = *(const short8*)(wbuf + co * 64 + swz16(co, g));
            }
            #pragma unroll
            for (int f = 0; f < 2; ++f) {
                int pix = r * XC + f * 32 + l31 + kwo;
                bfr[s][f] = *(const short8*)(xs + pix * 64 + swz16(pix, g));
            }
        }
        #pragma unroll
        for (int s = 0; s < 2; ++s)
            #pragma unroll
            for (int i = 0; i < 4; ++i)
                #pragma unroll
                for (int f = 0; f < 2; ++f)
                    acc[i][f] = __builtin_amdgcn_mfma_f32_32x32x16_bf16(
                        a[s][i], bfr[s][f], acc[i][f], 0, 0, 0);
        __syncthreads();

        if (kk == 8 && st < NSTEP - 1) {     // chunk boundary: restage x
            stageX(chunk + 1);
            __syncthreads();
        }
    }

    // ---- epilogue: 32x32 C/D layout col=lane&31 (pixel w), row=(reg&3)+8*(reg>>2)+4*(lane>>5) (co)
    float* op = out + (size_t)b * kCOUT * HW + (size_t)(h0 + wrow) * kW;
    #pragma unroll
    for (int i = 0; i < 4; ++i) {
        #pragma unroll
        for (int rg = 0; rg < 16; ++rg) {
            int co = cog + i * 32 + (rg & 3) + 8 * (rg >> 2) + 4 * hi2;
            float bv = bias[co];
            #pragma unroll
            for (int f = 0; f < 2; ++f) {
                op[(size_t)co * HW + f * 32 + l31] = acc[i][f][rg] + bv;
            }
        }
    }
}

extern "C" void kernel_launch(void* const* d_in, const int* in_sizes, int n_in,
                              void* d_out, int out_size, void* d_ws, size_t ws_size,
                              hipStream_t stream) {
    const float* x    = (const float*)d_in[0];
    const float* wsrc = (const float*)d_in[1];
    const float* bias = (const float*)d_in[2];
    float* out = (float*)d_out;
    unsigned short* wt = (unsigned short*)d_ws;  // 9*256*256*2 = 1.18 MB scratch

    hipLaunchKernelGGL(wt_transform_kernel, dim3((9 * 256 * 256 + 255) / 256),
                       dim3(256), 0, stream, wsrc, wt);

    hipLaunchKernelGGL(conv3x3_mfma_kernel, dim3(32 * (kH / ROWS)), dim3(BDIM),
                       0, stream, x, wt, bias, out);
}

// Round 3
// 192.466 us; speedup vs baseline: 1.0290x; 1.0290x over previous
//
#include <hip/hip_runtime.h>
#include <hip/hip_bf16.h>

typedef __attribute__((ext_vector_type(8))) short short8;
typedef __attribute__((ext_vector_type(16))) float floatx16;

#define BDIM 512

constexpr int kCIN = 256, kCOUT = 256, kH = 64, kW = 64;
constexpr int BK = 32;                  // ci per chunk
constexpr int NCHUNK = kCIN / BK;       // 8
constexpr int ROWS = 4;                 // output rows per block
constexpr int XR = ROWS + 2, XC = 66, NPIX = XR * XC;  // 396 halo pixels
constexpr int HW = kH * kW;
constexpr int NSTEP = NCHUNK * 9;       // 72

// K-major LDS layouts (all accesses contiguous per 32-lane half => conflict-free):
//   xs: [g=0..3][pix=0..NPIX-1][16B]          (granule g = ci sub-block of 8)
//   ws: [buf][g=0..3][co=0..255][16B]
constexpr int XS_PLANE = NPIX * 16;     // bytes per granule plane
constexpr int WS_PLANE = 256 * 16;
constexpr int WS_BUF   = 4 * WS_PLANE;  // 16 KB

__device__ __forceinline__ unsigned short f2bf(float f) {
    unsigned u = __float_as_uint(f);
    u += 0x7fffu + ((u >> 16) & 1u);   // RNE
    return (unsigned short)(u >> 16);
}

// weight[co][ci][kh][kw] fp32 -> wt2[kk][chunk][g][co][j] bf16
// (ci = chunk*32 + g*8 + j). Indexed so WRITES are fully coalesced.
__global__ void wt_transform_kernel(const float* __restrict__ wsrc,
                                    unsigned short* __restrict__ wt2) {
    int idx = blockIdx.x * 256 + threadIdx.x;
    if (idx >= 9 * 256 * 256) return;
    int j  = idx & 7;
    int co = (idx >> 3) & 255;
    int g  = (idx >> 11) & 3;
    int chunk = (idx >> 13) & 7;
    int kk = idx >> 16;
    int ci = chunk * 32 + g * 8 + j;
    wt2[idx] = f2bf(wsrc[(co * 256 + ci) * 9 + kk]);
}

// Block: 256 cout x 256 pixels (4 rows). 8 waves = 2(co-group) x 4(row).
// Wave tile: 128 co x 64 pix, 4x2 frags of 32x32x16 MFMA.
__global__ __launch_bounds__(BDIM, 2)
void conv3x3_mfma_kernel(const float* __restrict__ x,
                         const unsigned short* __restrict__ wt2,
                         const float* __restrict__ bias,
                         float* __restrict__ out) {
    __shared__ __align__(16) char xs[4 * XS_PLANE];   // 25.3 KB
    __shared__ __align__(16) char ws[2 * WS_BUF];     // 32.8 KB

    const int bid = blockIdx.x;
    const int b  = bid >> 4;            // 16 h-tiles per image
    const int h0 = (bid & 15) * ROWS;

    const int tid = threadIdx.x;
    const int wv  = tid >> 6;
    const int l   = tid & 63;
    const int l31 = l & 31;
    const int hi2 = l >> 5;
    const int cog  = (wv & 1) * 128;    // wave's cout base
    const int wrow = wv >> 1;           // wave's output row (0..3)

    const float* xb = x + (size_t)b * kCIN * HW;

    floatx16 acc[4][2] = {};            // [co frag][pix frag]

    // ---- W staging via global_load_lds: 16 wave-calls per tile, 2 per wave.
    // call c: g = c>>2, row0 = (c&3)*64; lane l -> co = row0 + l.
    // LDS dest (uniform): ws_buf + g*WS_PLANE + row0*16, DMA writes lane*16.
    // Global src (per-lane): wt2 + (((kk*8+chunk)*4+g)*256 + row0 + l)*8 -> contiguous.
    auto stageW = [&](int st, int chunk, int kk) {
        char* wbuf = ws + (st & 1) * WS_BUF;
        const unsigned short* wp = wt2 + (size_t)(kk * 8 + chunk) * 8192;
        #pragma unroll
        for (int it = 0; it < 2; ++it) {
            int c = wv * 2 + it;
            int g = c >> 2;
            int row0 = (c & 3) * 64;
            const unsigned short* src = wp + (g * 256 + row0 + l) * 8;
            __builtin_amdgcn_global_load_lds(
                (const __attribute__((address_space(1))) unsigned int*)src,
                (__attribute__((address_space(3))) unsigned int*)
                    (wbuf + g * WS_PLANE + row0 * 16),
                16, 0, 0);
        }
    };

    // ---- x halo staging: rows h0-1..h0+ROWS, cols -1..64, 32 ci, fp32->bf16 ----
    auto stageX = [&](int chunk) {
        const int ci0 = chunk * BK;
        for (int t = tid; t < NPIX * 4; t += BDIM) {
            int g = t / NPIX;
            int rem = t - g * NPIX;
            int r = rem / XC;
            int c = rem - r * XC;
            int ih = h0 - 1 + r;
            int iw = c - 1;
            float v[8];
            if ((unsigned)ih < (unsigned)kH && (unsigned)iw < (unsigned)kW) {
                const float* p = xb + (size_t)(ci0 + g * 8) * HW + ih * kW + iw;
                #pragma unroll
                for (int j = 0; j < 8; ++j) v[j] = p[(size_t)j * HW];
            } else {
                #pragma unroll
                for (int j = 0; j < 8; ++j) v[j] = 0.f;
            }
            union { short8 s8; unsigned short u[8]; } pk;
            #pragma unroll
            for (int j = 0; j < 8; ++j) pk.u[j] = f2bf(v[j]);
            int pix = r * XC + c;
            *(short8*)(xs + g * XS_PLANE + pix * 16) = pk.s8;
        }
    };

    stageX(0);
    stageW(0, 0, 0);
    __syncthreads();

    int chunk = 0, kk = 0;
    for (int st = 0; st < NSTEP; ++st) {
        int kk1 = kk + 1, chunk1 = chunk;
        if (kk1 == 9) { kk1 = 0; chunk1++; }
        if (st < NSTEP - 1) stageW(st + 1, chunk1, kk1);  // prefetch other buffer

        const char* wbuf = ws + (st & 1) * WS_BUF;
        const int kh = kk / 3, kwo = kk - kh * 3;
        const int r = wrow + kh;

        short8 a[2][4], bfr[2][2];
        #pragma unroll
        for (int s = 0; s < 2; ++s) {
            const int g = s * 2 + hi2;
            #pragma unroll
            for (int i = 0; i < 4; ++i) {
                int co = cog + i * 32 + l31;
                a[s][i] = *(const short8*)(wbuf + g * WS_PLANE + co * 16);
            }
            #pragma unroll
            for (int f = 0; f < 2; ++f) {
                int pix = r * XC + f * 32 + l31 + kwo;
                bfr[s][f] = *(const short8*)(xs + g * XS_PLANE + pix * 16);
            }
        }
        #pragma unroll
        for (int s = 0; s < 2; ++s)
            #pragma unroll
            for (int i = 0; i < 4; ++i)
                #pragma unroll
                for (int f = 0; f < 2; ++f)
                    acc[i][f] = __builtin_amdgcn_mfma_f32_32x32x16_bf16(
                        a[s][i], bfr[s][f], acc[i][f], 0, 0, 0);
        __syncthreads();

        if (kk == 8 && st < NSTEP - 1) {     // chunk boundary: restage x
            stageX(chunk1);
            __syncthreads();
        }
        kk = kk1; chunk = chunk1;
    }

    // ---- epilogue: 32x32 C/D: col=lane&31 (pixel w), row=(reg&3)+8*(reg>>2)+4*(lane>>5) (co)
    float* op = out + (size_t)b * kCOUT * HW + (size_t)(h0 + wrow) * kW;
    #pragma unroll
    for (int i = 0; i < 4; ++i) {
        #pragma unroll
        for (int rg = 0; rg < 16; ++rg) {
            int co = cog + i * 32 + (rg & 3) + 8 * (rg >> 2) + 4 * hi2;
            float bv = bias[co];
            #pragma unroll
            for (int f = 0; f < 2; ++f) {
                op[(size_t)co * HW + f * 32 + l31] = acc[i][f][rg] + bv;
            }
        }
    }
}

extern "C" void kernel_launch(void* const* d_in, const int* in_sizes, int n_in,
                              void* d_out, int out_size, void* d_ws, size_t ws_size,
                              hipStream_t stream) {
    const float* x    = (const float*)d_in[0];
    const float* wsrc = (const float*)d_in[1];
    const float* bias = (const float*)d_in[2];
    float* out = (float*)d_out;
    unsigned short* wt2 = (unsigned short*)d_ws;  // 9*256*256*2 = 1.18 MB scratch

    hipLaunchKernelGGL(wt_transform_kernel, dim3((9 * 256 * 256 + 255) / 256),
                       dim3(256), 0, stream, wsrc, wt2);

    hipLaunchKernelGGL(conv3x3_mfma_kernel, dim3(32 * (kH / ROWS)), dim3(BDIM),
                       0, stream, x, wt2, bias, out);
}